// Round 6
// baseline (388.885 us; speedup 1.0000x reference)
//
#include <hip/hip_runtime.h>
#include <cstddef>
#include <cstdint>

typedef unsigned short u16;
typedef short s16x8 __attribute__((ext_vector_type(8)));
typedef float f32x4 __attribute__((ext_vector_type(4)));
typedef int   i32x4 __attribute__((ext_vector_type(4)));
typedef u16   u16x4 __attribute__((ext_vector_type(4)));

__device__ __forceinline__ float b2f(u16 u) {
  union { unsigned int i; float f; } v; v.i = ((unsigned int)u) << 16; return v.f;
}
__device__ __forceinline__ u16 f2b(float f) {
  union { float f; unsigned int i; } v; v.f = f;
  unsigned int r = v.i + 0x7fffu + ((v.i >> 16) & 1u);
  return (u16)(r >> 16);
}
// pack 2 fp32 -> 2 bf16 (RNE) in one instruction; low 16 bits = a.
__device__ __forceinline__ unsigned int cvt_pk(float a, float b) {
  unsigned int r;
  asm("v_cvt_pk_bf16_f32 %0, %1, %2" : "=v"(r) : "v"(a), "v"(b));
  return r;
}

// ---------------------------------------------------------------------------
// Transpose+cast 6 fp32 weight matrices (256x256) -> bf16 WT[n][k].
// grid (6,16) x 256 thr; 64x64 tile per block.
// ---------------------------------------------------------------------------
__global__ __launch_bounds__(256) void transpose6(
    const float* __restrict__ w0, const float* __restrict__ w1,
    const float* __restrict__ w2, const float* __restrict__ w3,
    const float* __restrict__ w4, const float* __restrict__ w5,
    u16* __restrict__ wt)
{
  __shared__ u16 T[64][66];
  const float* src;
  switch (blockIdx.x) {
    case 0: src = w0; break; case 1: src = w1; break;
    case 2: src = w2; break; case 3: src = w3; break;
    case 4: src = w4; break; default: src = w5; break;
  }
  u16* dst = wt + (size_t)blockIdx.x * 65536;
  const int tr = (blockIdx.y & 3) * 64;
  const int tc = (blockIdx.y >> 2) * 64;
  const int lane = threadIdx.x & 63, grp = threadIdx.x >> 6;
  #pragma unroll
  for (int i = 0; i < 16; ++i) {
    const int r = grp + i * 4;
    T[lane][r] = f2b(src[(size_t)(tr + r) * 256 + tc + lane]);
  }
  __syncthreads();
  #pragma unroll
  for (int i = 0; i < 16; ++i) {
    const int j = grp + i * 4;
    dst[(size_t)(tc + j) * 256 + tr + lane] = T[j][lane];
  }
}

// ---------------------------------------------------------------------------
// FiLM precompute (fp32): emb = pos(256x256) @ W_emb(256x512) + b_emb
// grid (256,8) x 256 thr.
// ---------------------------------------------------------------------------
__global__ __launch_bounds__(256) void film_kernel(
    const float* __restrict__ pos, const float* __restrict__ Wemb,
    const float* __restrict__ bemb, float* __restrict__ shift,
    float* __restrict__ scale)
{
  __shared__ float prow[256];
  __shared__ float psum[4][64];
  const int s = blockIdx.x, t = threadIdx.x;
  const int ks = t >> 6, cl = t & 63;
  const int c = blockIdx.y * 64 + cl;
  prow[t] = pos[s * 256 + t];
  __syncthreads();
  float acc = 0.f;
  #pragma unroll 8
  for (int kk = ks * 64; kk < ks * 64 + 64; ++kk)
    acc = fmaf(prow[kk], Wemb[kk * 512 + c], acc);
  psum[ks][cl] = acc;
  __syncthreads();
  if (t < 64) {
    const int cc = blockIdx.y * 64 + t;
    const float v = psum[0][t] + psum[1][t] + psum[2][t] + psum[3][t] + bemb[cc];
    if (cc < 256) shift[s * 256 + cc] = v;
    else          scale[s * 256 + cc - 256] = v;
  }
}

// ---------------------------------------------------------------------------
// LayerNorm (fp32 + FiLM): token owned by a 16-lane group. grid 4096 x 256.
// ---------------------------------------------------------------------------
__global__ __launch_bounds__(256) void ln_kernel(
    const float* __restrict__ xf,
    const float* __restrict__ shift, const float* __restrict__ scale,
    const float* __restrict__ g, const float* __restrict__ b,
    u16* __restrict__ out)
{
  const int lane = threadIdx.x & 63;
  const int l = lane & 15, grp = lane >> 4;
  const int token = blockIdx.x * 16 + (threadIdx.x >> 6) * 4 + grp;
  const size_t tb = (size_t)token * 256;
  const int spos = token & 255;

  f32x4 v[4];
  #pragma unroll
  for (int j = 0; j < 4; ++j) v[j] = *(const f32x4*)(xf + tb + 4 * l + 64 * j);
  float s = 0.f, s2 = 0.f;
  #pragma unroll
  for (int j = 0; j < 4; ++j)
    #pragma unroll
    for (int i = 0; i < 4; ++i) { s += v[j][i]; s2 += v[j][i] * v[j][i]; }
  #pragma unroll
  for (int off = 8; off >= 1; off >>= 1) {
    s  += __shfl_xor(s, off);
    s2 += __shfl_xor(s2, off);
  }
  const float mean = s * 0.00390625f;
  const float inv  = rsqrtf(s2 * 0.00390625f - mean * mean + 1e-5f);
  #pragma unroll
  for (int j = 0; j < 4; ++j) {
    const int e = 4 * l + 64 * j;
    const f32x4 gv = *(const f32x4*)(g + e);
    const f32x4 bv = *(const f32x4*)(b + e);
    const f32x4 sc = *(const f32x4*)(scale + spos * 256 + e);
    const f32x4 sh = *(const f32x4*)(shift + spos * 256 + e);
    u16x4 o;
    #pragma unroll
    for (int i = 0; i < 4; ++i) {
      float ln = (v[j][i] - mean) * inv * gv[i] + bv[i];
      ln = ln * (sc[i] + 1.0f) + sh[i];
      o[i] = f2b(ln);
    }
    *(u16x4*)(out + tb + e) = o;
  }
}

// ---------------------------------------------------------------------------
// Fused QKV GEMM: A(65536x256) bf16 @ {WqT,WkT,WvT}.
// Flat grid 3072, XCD-aware decode: all 6 blocks sharing an A-tile (same y)
// carry the same id%8 -> same XCD L2.
// q,k stored head-major [w][h][t][32]; v stored key-permuted for the
// swapped-QK attention.
// ---------------------------------------------------------------------------
__global__ __launch_bounds__(256) void gemm_qkv(
    const u16* __restrict__ A, const u16* __restrict__ wt,
    const float* __restrict__ bq, const float* __restrict__ bk,
    const float* __restrict__ bv, u16* __restrict__ qo,
    u16* __restrict__ ko, u16* __restrict__ vo)
{
  __shared__ __align__(16) u16 Alds[128][72];
  __shared__ __align__(16) u16 Blds[128][72];
  const int bid = blockIdx.x;
  const int xcd = bid & 7, rr = bid >> 3;
  const int xx = rr % 6;                   // weight*2 + n-half
  const int yy = (rr / 6) * 8 + xcd;       // m-block 0..511
  const int wsel = xx >> 1;
  const int m0 = yy * 128;
  const int n0 = (xx & 1) * 128;
  const u16* BT = wt + (size_t)wsel * 65536;
  const int t = threadIdx.x;
  const int wave = t >> 6, lane = t & 63;
  const int wm = (wave & 1) * 64, wn = (wave >> 1) * 64;
  const int lrow = lane & 15, lk = (lane >> 4) * 8;

  f32x4 acc[4][4];
  #pragma unroll
  for (int i = 0; i < 4; ++i)
    #pragma unroll
    for (int j = 0; j < 4; ++j)
      acc[i][j] = f32x4{0.f, 0.f, 0.f, 0.f};

  for (int k0 = 0; k0 < 256; k0 += 64) {
    #pragma unroll
    for (int i = 0; i < 4; ++i) {
      const int c = i * 256 + t;
      const int row = c >> 3, col = (c & 7) * 8;
      *(i32x4*)(&Alds[row][col]) = *(const i32x4*)(A  + (size_t)(m0 + row) * 256 + k0 + col);
      *(i32x4*)(&Blds[row][col]) = *(const i32x4*)(BT + (size_t)(n0 + row) * 256 + k0 + col);
    }
    __syncthreads();
    #pragma unroll
    for (int kk = 0; kk < 64; kk += 32) {
      s16x8 af[4], bf[4];
      #pragma unroll
      for (int mt = 0; mt < 4; ++mt) af[mt] = *(const s16x8*)(&Alds[wm + mt*16 + lrow][kk + lk]);
      #pragma unroll
      for (int nt = 0; nt < 4; ++nt) bf[nt] = *(const s16x8*)(&Blds[wn + nt*16 + lrow][kk + lk]);
      #pragma unroll
      for (int mt = 0; mt < 4; ++mt)
        #pragma unroll
        for (int nt = 0; nt < 4; ++nt)
          acc[mt][nt] = __builtin_amdgcn_mfma_f32_16x16x32_bf16(af[mt], bf[nt], acc[mt][nt], 0, 0, 0);
    }
    __syncthreads();
  }

  const float* bias = (wsel == 0) ? bq : (wsel == 1) ? bk : bv;
  u16* qko = (wsel == 0) ? qo : ko;
  #pragma unroll
  for (int mt = 0; mt < 4; ++mt) {
    const int mb = m0 + wm + mt*16 + (lane >> 4) * 4;
    const int w = mb >> 8, tok = mb & 255;
    #pragma unroll
    for (int nt = 0; nt < 4; ++nt) {
      const int n = n0 + wn + nt*16 + lrow;
      const int h = n >> 5, d = n & 31;
      const float bv_ = bias[n];
      if (wsel < 2) {
        #pragma unroll
        for (int r = 0; r < 4; ++r)
          qko[(size_t)w * 65536 + h * 8192 + (tok + r) * 32 + d] = f2b(acc[mt][nt][r] + bv_);
      } else {
        // tok % 4 == 0 -> the 4 keys tok..tok+3 are contiguous at this addr.
        u16x4 pk;
        #pragma unroll
        for (int r = 0; r < 4; ++r) pk[r] = f2b(acc[mt][nt][r] + bv_);
        const int vaddr = ((tok >> 5) << 10) + (((tok >> 2) & 3) << 8)
                        + d * 8 + (((tok >> 4) & 1) << 2);
        *(u16x4*)(vo + (size_t)w * 65536 + h * 8192 + vaddr) = pk;
      }
    }
  }
}

// ---------------------------------------------------------------------------
// Fused tail v2: x1 = x + gam*(A@WoT + bo) (bf16 in regs); LN2 in-block;
// H = silu(xn@W1T) in XH LDS (XOR-swizzled); out = b2f(x1) + gml*(H@W2T).
// Weight fragments read DIRECT from global (L2-resident 3x128KB) -> no
// panel staging, no per-panel barriers (5 barriers total).
// XH swizzle: 16B-block index ^= (row>>2)&3  (col ^= (row&12)<<1) ->
// scalar LN/silu writes cover all 8 bank groups; b128 reads uniform.
// grid 1024 x 512 thr (8 waves: 2m x 4n). LDS ~36 KB -> 3 blocks/CU.
// ---------------------------------------------------------------------------
__global__ __launch_bounds__(512) void gemm_tail(
    const u16* __restrict__ A, const u16* __restrict__ WoT,
    const u16* __restrict__ W1T, const u16* __restrict__ W2T,
    const float* __restrict__ bo, const float* __restrict__ x,
    const float* __restrict__ gam, const float* __restrict__ lg2,
    const float* __restrict__ lb2, const float* __restrict__ gml,
    float* __restrict__ outx)
{
  __shared__ __align__(16) u16 XH[64][264];
  __shared__ float LNp[4][64][2];
  __shared__ float LNm[64][2];
  const int m0 = blockIdx.x * 64;
  const int t = threadIdx.x;
  const int wave = t >> 6, lane = t & 63;
  const int wm = (wave & 1) * 32, wn = (wave >> 1) * 64;
  const int lrow = lane & 15, lk = (lane >> 4) * 8;
  const int quad = lane >> 4, col = lane & 15;

  f32x4 acc[2][4];
  #pragma unroll
  for (int i = 0; i < 2; ++i)
    #pragma unroll
    for (int j = 0; j < 4; ++j) acc[i][j] = f32x4{0.f,0.f,0.f,0.f};

  // ================= phase A: acc = A @ WoT (all direct-global) ============
  #pragma unroll 2
  for (int k0 = 0; k0 < 256; k0 += 32) {
    s16x8 af[2], bf[4];
    #pragma unroll
    for (int mt = 0; mt < 2; ++mt)
      af[mt] = *(const s16x8*)(A + (size_t)(m0 + wm + mt*16 + lrow) * 256 + k0 + lk);
    #pragma unroll
    for (int nt = 0; nt < 4; ++nt)
      bf[nt] = *(const s16x8*)(WoT + (size_t)(wn + nt*16 + lrow) * 256 + k0 + lk);
    #pragma unroll
    for (int mt = 0; mt < 2; ++mt)
      #pragma unroll
      for (int nt = 0; nt < 4; ++nt)
        acc[mt][nt] = __builtin_amdgcn_mfma_f32_16x16x32_bf16(af[mt], bf[nt], acc[mt][nt], 0, 0, 0);
  }

  // ---- epilogue A: x1 (bf16 in regs) + LN partial sums
  unsigned int x1p[2][4][2];
  float s[2][4], s2[2][4];
  #pragma unroll
  for (int mt = 0; mt < 2; ++mt)
    #pragma unroll
    for (int r = 0; r < 4; ++r) { s[mt][r] = 0.f; s2[mt][r] = 0.f; }

  #pragma unroll
  for (int mt = 0; mt < 2; ++mt) {
    const int mb = m0 + wm + mt*16 + quad*4;
    #pragma unroll
    for (int nt = 0; nt < 4; ++nt) {
      const int n = wn + nt*16 + col;
      const float bon = bo[n], gn = gam[n];
      float v[4];
      #pragma unroll
      for (int r = 0; r < 4; ++r)
        v[r] = x[(size_t)(mb + r) * 256 + n] + gn * (acc[mt][nt][r] + bon);
      const unsigned int p0 = cvt_pk(v[0], v[1]);
      const unsigned int p1 = cvt_pk(v[2], v[3]);
      x1p[mt][nt][0] = p0;
      x1p[mt][nt][1] = p1;
      const float r0 = b2f((u16)(p0 & 0xffffu)), r1 = b2f((u16)(p0 >> 16));
      const float r2 = b2f((u16)(p1 & 0xffffu)), r3 = b2f((u16)(p1 >> 16));
      s[mt][0] += r0; s2[mt][0] += r0 * r0;
      s[mt][1] += r1; s2[mt][1] += r1 * r1;
      s[mt][2] += r2; s2[mt][2] += r2 * r2;
      s[mt][3] += r3; s2[mt][3] += r3 * r3;
    }
  }
  // intra-wave reduce over the 16 col lanes
  #pragma unroll
  for (int off = 1; off <= 8; off <<= 1) {
    #pragma unroll
    for (int mt = 0; mt < 2; ++mt)
      #pragma unroll
      for (int r = 0; r < 4; ++r) {
        s[mt][r]  += __shfl_xor(s[mt][r],  off);
        s2[mt][r] += __shfl_xor(s2[mt][r], off);
      }
  }
  if (col == 0) {
    #pragma unroll
    for (int mt = 0; mt < 2; ++mt)
      #pragma unroll
      for (int r = 0; r < 4; ++r) {
        const int row = wm + mt*16 + quad*4 + r;
        LNp[wave >> 1][row][0] = s[mt][r];
        LNp[wave >> 1][row][1] = s2[mt][r];
      }
  }
  __syncthreads();
  if (t < 64) {
    const float ss  = LNp[0][t][0] + LNp[1][t][0] + LNp[2][t][0] + LNp[3][t][0];
    const float ss2 = LNp[0][t][1] + LNp[1][t][1] + LNp[2][t][1] + LNp[3][t][1];
    const float mean = ss * 0.00390625f;
    LNm[t][0] = mean;
    LNm[t][1] = rsqrtf(ss2 * 0.00390625f - mean * mean + 1e-5f);
  }
  __syncthreads();
  // xn -> XH (swizzled)
  #pragma unroll
  for (int mt = 0; mt < 2; ++mt) {
    #pragma unroll
    for (int nt = 0; nt < 4; ++nt) {
      const int n = wn + nt*16 + col;
      const float gg = lg2[n], bb_ = lb2[n];
      #pragma unroll
      for (int rr = 0; rr < 2; ++rr) {
        const unsigned int pk = x1p[mt][nt][rr];
        #pragma unroll
        for (int h2 = 0; h2 < 2; ++h2) {
          const int r = rr * 2 + h2;
          const int row = wm + mt*16 + quad*4 + r;
          const float rv = b2f((u16)(h2 ? (pk >> 16) : (pk & 0xffffu)));
          const float xn = (rv - LNm[row][0]) * LNm[row][1] * gg + bb_;
          XH[row][n ^ ((row & 12) << 1)] = f2b(xn);
        }
      }
    }
  }
  __syncthreads();

  // ================= phase B: acc = XH @ W1T (W direct-global) =============
  #pragma unroll
  for (int i = 0; i < 2; ++i)
    #pragma unroll
    for (int j = 0; j < 4; ++j) acc[i][j] = f32x4{0.f,0.f,0.f,0.f};
  #pragma unroll 2
  for (int k0 = 0; k0 < 256; k0 += 32) {
    s16x8 af[2], bf[4];
    #pragma unroll
    for (int mt = 0; mt < 2; ++mt) {
      const int row = wm + mt*16 + lrow;
      af[mt] = *(const s16x8*)(&XH[row][(k0 + lk) ^ ((row & 12) << 1)]);
    }
    #pragma unroll
    for (int nt = 0; nt < 4; ++nt)
      bf[nt] = *(const s16x8*)(W1T + (size_t)(wn + nt*16 + lrow) * 256 + k0 + lk);
    #pragma unroll
    for (int mt = 0; mt < 2; ++mt)
      #pragma unroll
      for (int nt = 0; nt < 4; ++nt)
        acc[mt][nt] = __builtin_amdgcn_mfma_f32_16x16x32_bf16(af[mt], bf[nt], acc[mt][nt], 0, 0, 0);
  }
  __syncthreads();   // all XH reads done before overwrite
  // silu -> H overwrites XH (swizzled)
  #pragma unroll
  for (int mt = 0; mt < 2; ++mt)
    #pragma unroll
    for (int nt = 0; nt < 4; ++nt)
      #pragma unroll
      for (int r = 0; r < 4; ++r) {
        const float y = acc[mt][nt][r];
        const float hsig = __builtin_amdgcn_rcpf(1.0f + __builtin_amdgcn_exp2f(-1.442695041f * y));
        const int row = wm + mt*16 + quad*4 + r;
        const int n = wn + nt*16 + col;
        XH[row][n ^ ((row & 12) << 1)] = f2b(y * hsig);
        acc[mt][nt][r] = 0.0f;
      }
  __syncthreads();

  // ================= phase C: acc = H @ W2T (W direct-global) ==============
  #pragma unroll 2
  for (int k0 = 0; k0 < 256; k0 += 32) {
    s16x8 af[2], bf[4];
    #pragma unroll
    for (int mt = 0; mt < 2; ++mt) {
      const int row = wm + mt*16 + lrow;
      af[mt] = *(const s16x8*)(&XH[row][(k0 + lk) ^ ((row & 12) << 1)]);
    }
    #pragma unroll
    for (int nt = 0; nt < 4; ++nt)
      bf[nt] = *(const s16x8*)(W2T + (size_t)(wn + nt*16 + lrow) * 256 + k0 + lk);
    #pragma unroll
    for (int mt = 0; mt < 2; ++mt)
      #pragma unroll
      for (int nt = 0; nt < 4; ++nt)
        acc[mt][nt] = __builtin_amdgcn_mfma_f32_16x16x32_bf16(af[mt], bf[nt], acc[mt][nt], 0, 0, 0);
  }

  // ---- epilogue C: out = b2f(x1) + gml[n]*acc
  #pragma unroll
  for (int mt = 0; mt < 2; ++mt) {
    const int mb = m0 + wm + mt*16 + quad*4;
    #pragma unroll
    for (int nt = 0; nt < 4; ++nt) {
      const int n = wn + nt*16 + col;
      const float gn = gml[n];
      #pragma unroll
      for (int rr = 0; rr < 2; ++rr) {
        const unsigned int pk = x1p[mt][nt][rr];
        outx[(size_t)(mb + rr*2    ) * 256 + n] = b2f((u16)(pk & 0xffffu)) + gn * acc[mt][nt][rr*2];
        outx[(size_t)(mb + rr*2 + 1) * 256 + n] = b2f((u16)(pk >> 16))     + gn * acc[mt][nt][rr*2 + 1];
      }
    }
  }
}

// ---------------------------------------------------------------------------
// Attention v6: flat grid 4096 x 512 thr (8 waves, 16 queries each),
// XCD-aware decode: the 2 blocks sharing a (w,h) K/V slice -> same XCD.
// K+V (32 KB) staged once per block into LDS; swapped-QK register softmax;
// P feeds PV MFMA directly from registers (V key-permuted by gemm_qkv).
// ---------------------------------------------------------------------------
__global__ __launch_bounds__(512) void attn256(
    const u16* __restrict__ q, const u16* __restrict__ k,
    const u16* __restrict__ vt, const float* __restrict__ fbias,
    u16* __restrict__ out)
{
  __shared__ __align__(16) u16 KV[16384];     // K bytes [0,16K) | V bytes [16K,32K)
  __shared__ __align__(16) u16 OB[8][16][40];
  const int bid = blockIdx.x;
  const int xcd = bid & 7, rr = bid >> 3;
  const int q0 = (rr & 1) * 128;
  const int s_ = (rr >> 1) * 8 + xcd;        // 0..2047
  const int h = s_ & 7, w = s_ >> 3;
  const int t = threadIdx.x;
  const int wave = t >> 6, lane = t & 63;
  const int col = lane & 15, quad = lane >> 4;
  const size_t hb = (size_t)w * 65536 + (size_t)h * 8192;
  const int qr0 = q0 + wave * 16;
  const float sc2 = 0.25508586f;  // (1/sqrt(32)) * log2(e)

  // ---- stage K and V (64B per thread each), linear copy
  {
    const char* kg = (const char*)(k + hb);
    const char* vg = (const char*)(vt + hb);
    const i32x4 r0 = *(const i32x4*)(kg + t * 16);
    const i32x4 r1 = *(const i32x4*)(kg + 8192 + t * 16);
    const i32x4 r2 = *(const i32x4*)(vg + t * 16);
    const i32x4 r3 = *(const i32x4*)(vg + 8192 + t * 16);
    char* lb = (char*)KV;
    *(i32x4*)(lb + t * 16)         = r0;
    *(i32x4*)(lb + 8192 + t * 16)  = r1;
    *(i32x4*)(lb + 16384 + t * 16) = r2;
    *(i32x4*)(lb + 24576 + t * 16) = r3;
  }

  // Q fragment + mask bias (global; overlap with stage)
  const s16x8 af = *(const s16x8*)(q + hb + (qr0 + col) * 32 + quad * 8);
  const float* fbb = fbias + w * 256 + quad * 4;
  __syncthreads();

  // ---- QK^T swapped (K from LDS): acc[tl][r] = S[key=tl*16+quad*4+r][q=col]
  f32x4 acc[16];
  #pragma unroll
  for (int tl = 0; tl < 16; ++tl) {
    const s16x8 kf = *(const s16x8*)(KV + (tl * 16 + col) * 32 + quad * 8);
    acc[tl] = __builtin_amdgcn_mfma_f32_16x16x32_bf16(kf, af, f32x4{0.f,0.f,0.f,0.f}, 0, 0, 0);
  }

  // ---- scale + mask bias
  #pragma unroll
  for (int tl = 0; tl < 16; ++tl) {
    const f32x4 fb = *(const f32x4*)(fbb + tl * 16);
    #pragma unroll
    for (int r = 0; r < 4; ++r)
      acc[tl][r] = fmaf(acc[tl][r], sc2, fb[r]);
  }

  // ---- lane-local max over 64 keys, then cross-quad (2 shuffles)
  f32x4 m4 = acc[0];
  #pragma unroll
  for (int tl = 1; tl < 16; ++tl)
    #pragma unroll
    for (int r = 0; r < 4; ++r)
      m4[r] = fmaxf(m4[r], acc[tl][r]);
  float mx = fmaxf(fmaxf(m4[0], m4[1]), fmaxf(m4[2], m4[3]));
  mx = fmaxf(mx, __shfl_xor(mx, 16));
  mx = fmaxf(mx, __shfl_xor(mx, 32));

  // ---- exp2 + lane-local sum, then cross-quad (2 shuffles)
  f32x4 s4 = {0.f, 0.f, 0.f, 0.f};
  #pragma unroll
  for (int tl = 0; tl < 16; ++tl) {
    #pragma unroll
    for (int r = 0; r < 4; ++r) {
      const float e = __builtin_amdgcn_exp2f(acc[tl][r] - mx);
      acc[tl][r] = e;
      s4[r] += e;
    }
  }
  float sum = (s4[0] + s4[1]) + (s4[2] + s4[3]);
  sum += __shfl_xor(sum, 16);
  sum += __shfl_xor(sum, 32);
  const float inv = __builtin_amdgcn_rcpf(sum);

  // ---- PV from registers (V from LDS, pre-permuted)
  f32x4 o0 = {0.f,0.f,0.f,0.f}, o1 = {0.f,0.f,0.f,0.f};
  const u16* vl = KV + 8192;
  #pragma unroll
  for (int s = 0; s < 8; ++s) {
    i32x4 pi;
    pi[0] = (int)cvt_pk(acc[2*s][0],     acc[2*s][1]);
    pi[1] = (int)cvt_pk(acc[2*s][2],     acc[2*s][3]);
    pi[2] = (int)cvt_pk(acc[2*s + 1][0], acc[2*s + 1][1]);
    pi[3] = (int)cvt_pk(acc[2*s + 1][2], acc[2*s + 1][3]);
    const s16x8 pf = *(const s16x8*)&pi;
    const s16x8 vf0 = *(const s16x8*)(vl + s * 1024 + quad * 256 + col * 8);
    const s16x8 vf1 = *(const s16x8*)(vl + s * 1024 + quad * 256 + col * 8 + 128);
    o0 = __builtin_amdgcn_mfma_f32_16x16x32_bf16(pf, vf0, o0, 0, 0, 0);
    o1 = __builtin_amdgcn_mfma_f32_16x16x32_bf16(pf, vf1, o1, 0, 0, 0);
  }

  // ---- 1/sum for output rows q = quad*4+r lives at lane (*, quad*4+r)
  f32x4 invr;
  #pragma unroll
  for (int r = 0; r < 4; ++r) invr[r] = __shfl(inv, quad * 4 + r);

  // ---- bounce O through LDS for 16B/lane stores (wave-private slab)
  #pragma unroll
  for (int r = 0; r < 4; ++r) {
    OB[wave][quad * 4 + r][col]      = f2b(o0[r] * invr[r]);
    OB[wave][quad * 4 + r][col + 16] = f2b(o1[r] * invr[r]);
  }
  const s16x8 ov = *(const s16x8*)(&OB[wave][col][quad * 8]);
  *(s16x8*)(out + (size_t)w * 65536 + (size_t)(qr0 + col) * 256 + h * 32 + quad * 8) = ov;
}

// ---------------------------------------------------------------------------
// mask_update + attention bias precompute. grid 256 x 256.
// ---------------------------------------------------------------------------
__global__ __launch_bounds__(256) void maskup(const int* __restrict__ mask,
                                              float* __restrict__ out,
                                              float* __restrict__ fbias)
{
  __shared__ int wall[4];
  const int w = blockIdx.x, t = threadIdx.x;
  const int v = (mask[w * 256 + t] != 0) ? 1 : 0;
  const int a = __all(v);
  if ((t & 63) == 0) wall[t >> 6] = a;
  __syncthreads();
  const int allw = wall[0] & wall[1] & wall[2] & wall[3];
  out[w * 256 + t] = (v & allw) ? 1.0f : 0.0f;
  fbias[w * 256 + t] = v ? 0.0f : -1.0e9f;
}

// ---------------------------------------------------------------------------
extern "C" void kernel_launch(void* const* d_in, const int* in_sizes, int n_in,
                              void* d_out, int out_size, void* d_ws, size_t ws_size,
                              hipStream_t stream)
{
  (void)in_sizes; (void)n_in; (void)out_size; (void)ws_size;
  const float* x    = (const float*)d_in[0];
  const int*   mask = (const int*)d_in[1];
  const float* pos  = (const float*)d_in[2];
  const float* Wemb = (const float*)d_in[3];
  const float* bemb = (const float*)d_in[4];
  const float* ln1g = (const float*)d_in[5];
  const float* ln1b = (const float*)d_in[6];
  const float* Wq   = (const float*)d_in[7];
  const float* bq   = (const float*)d_in[8];
  const float* Wk   = (const float*)d_in[9];
  const float* bk   = (const float*)d_in[10];
  const float* Wv   = (const float*)d_in[11];
  const float* bv   = (const float*)d_in[12];
  const float* Wo   = (const float*)d_in[13];
  const float* bo   = (const float*)d_in[14];
  const float* ln2g = (const float*)d_in[15];
  const float* ln2b = (const float*)d_in[16];
  const float* W1   = (const float*)d_in[17];
  const float* W2   = (const float*)d_in[18];
  const float* gam  = (const float*)d_in[19];
  const float* gml  = (const float*)d_in[20];

  char* ws = (char*)d_ws;
  float* shift = (float*)ws;                       // 256 KB
  float* scale = (float*)(ws + (256 << 10));       // 256 KB
  u16*   wt    = (u16*)(ws + (512 << 10));         // 768 KB (6 x 256x256)
  float* fbias = (float*)(ws + (1280 << 10));      // 256 KB
  u16*   b0    = (u16*)(ws + ((size_t)2  << 20));  // xm   -> attn_out
  u16*   b1    = (u16*)(ws + ((size_t)34 << 20));  // q^
  u16*   b2    = (u16*)(ws + ((size_t)66 << 20));  // k^
  u16*   b3    = (u16*)(ws + ((size_t)98 << 20));  // V~
  float* outx  = (float*)d_out;
  float* outm  = outx + 16777216;

  const u16* WoT = wt + 3 * 65536;
  const u16* W1T = wt + 4 * 65536;
  const u16* W2T = wt + 5 * 65536;

  transpose6<<<dim3(6, 16), 256, 0, stream>>>(Wq, Wk, Wv, Wo, W1, W2, wt);
  film_kernel<<<dim3(256, 8), 256, 0, stream>>>(pos, Wemb, bemb, shift, scale);
  maskup<<<256, 256, 0, stream>>>(mask, outm, fbias);
  ln_kernel<<<4096, 256, 0, stream>>>(x, shift, scale, ln1g, ln1b, b0);
  gemm_qkv<<<3072, 256, 0, stream>>>(b0, wt, bq, bk, bv, b1, b2, b3);
  attn256<<<4096, 512, 0, stream>>>(b1, b2, b3, fbias, b0);
  // fused tail: Wo-residual + LN2 + MLP, single pass over the activations
  gemm_tail<<<1024, 512, 0, stream>>>(b0, WoT, W1T, W2T, bo, x, gam,
                                      ln2g, ln2b, gml, outx);
}

// Round 7
// 345.416 us; speedup vs baseline: 1.1258x; 1.1258x over previous
//
#include <hip/hip_runtime.h>
#include <cstddef>
#include <cstdint>

typedef unsigned short u16;
typedef short s16x8 __attribute__((ext_vector_type(8)));
typedef float f32x4 __attribute__((ext_vector_type(4)));
typedef int   i32x4 __attribute__((ext_vector_type(4)));
typedef u16   u16x4 __attribute__((ext_vector_type(4)));

__device__ __forceinline__ float b2f(u16 u) {
  union { unsigned int i; float f; } v; v.i = ((unsigned int)u) << 16; return v.f;
}
__device__ __forceinline__ u16 f2b(float f) {
  union { float f; unsigned int i; } v; v.f = f;
  unsigned int r = v.i + 0x7fffu + ((v.i >> 16) & 1u);
  return (u16)(r >> 16);
}
// pack 2 fp32 -> 2 bf16 (RNE) in one instruction; low 16 bits = a.
__device__ __forceinline__ unsigned int cvt_pk(float a, float b) {
  unsigned int r;
  asm("v_cvt_pk_bf16_f32 %0, %1, %2" : "=v"(r) : "v"(a), "v"(b));
  return r;
}

// ---------------------------------------------------------------------------
// Transpose+cast 6 fp32 weight matrices (256x256) -> bf16 WT[n][k].
// grid (6,16) x 256 thr; 64x64 tile per block.
// ---------------------------------------------------------------------------
__global__ __launch_bounds__(256) void transpose6(
    const float* __restrict__ w0, const float* __restrict__ w1,
    const float* __restrict__ w2, const float* __restrict__ w3,
    const float* __restrict__ w4, const float* __restrict__ w5,
    u16* __restrict__ wt)
{
  __shared__ u16 T[64][66];
  const float* src;
  switch (blockIdx.x) {
    case 0: src = w0; break; case 1: src = w1; break;
    case 2: src = w2; break; case 3: src = w3; break;
    case 4: src = w4; break; default: src = w5; break;
  }
  u16* dst = wt + (size_t)blockIdx.x * 65536;
  const int tr = (blockIdx.y & 3) * 64;
  const int tc = (blockIdx.y >> 2) * 64;
  const int lane = threadIdx.x & 63, grp = threadIdx.x >> 6;
  #pragma unroll
  for (int i = 0; i < 16; ++i) {
    const int r = grp + i * 4;
    T[lane][r] = f2b(src[(size_t)(tr + r) * 256 + tc + lane]);
  }
  __syncthreads();
  #pragma unroll
  for (int i = 0; i < 16; ++i) {
    const int j = grp + i * 4;
    dst[(size_t)(tc + j) * 256 + tr + lane] = T[j][lane];
  }
}

// ---------------------------------------------------------------------------
// FiLM precompute (fp32): emb = pos(256x256) @ W_emb(256x512) + b_emb
// grid (256,8) x 256 thr.
// ---------------------------------------------------------------------------
__global__ __launch_bounds__(256) void film_kernel(
    const float* __restrict__ pos, const float* __restrict__ Wemb,
    const float* __restrict__ bemb, float* __restrict__ shift,
    float* __restrict__ scale)
{
  __shared__ float prow[256];
  __shared__ float psum[4][64];
  const int s = blockIdx.x, t = threadIdx.x;
  const int ks = t >> 6, cl = t & 63;
  const int c = blockIdx.y * 64 + cl;
  prow[t] = pos[s * 256 + t];
  __syncthreads();
  float acc = 0.f;
  #pragma unroll 8
  for (int kk = ks * 64; kk < ks * 64 + 64; ++kk)
    acc = fmaf(prow[kk], Wemb[kk * 512 + c], acc);
  psum[ks][cl] = acc;
  __syncthreads();
  if (t < 64) {
    const int cc = blockIdx.y * 64 + t;
    const float v = psum[0][t] + psum[1][t] + psum[2][t] + psum[3][t] + bemb[cc];
    if (cc < 256) shift[s * 256 + cc] = v;
    else          scale[s * 256 + cc - 256] = v;
  }
}

// ---------------------------------------------------------------------------
// LayerNorm (fp32 + FiLM): token owned by a 16-lane group. grid 4096 x 256.
// ---------------------------------------------------------------------------
__global__ __launch_bounds__(256) void ln_kernel(
    const float* __restrict__ xf,
    const float* __restrict__ shift, const float* __restrict__ scale,
    const float* __restrict__ g, const float* __restrict__ b,
    u16* __restrict__ out)
{
  const int lane = threadIdx.x & 63;
  const int l = lane & 15, grp = lane >> 4;
  const int token = blockIdx.x * 16 + (threadIdx.x >> 6) * 4 + grp;
  const size_t tb = (size_t)token * 256;
  const int spos = token & 255;

  f32x4 v[4];
  #pragma unroll
  for (int j = 0; j < 4; ++j) v[j] = *(const f32x4*)(xf + tb + 4 * l + 64 * j);
  float s = 0.f, s2 = 0.f;
  #pragma unroll
  for (int j = 0; j < 4; ++j)
    #pragma unroll
    for (int i = 0; i < 4; ++i) { s += v[j][i]; s2 += v[j][i] * v[j][i]; }
  #pragma unroll
  for (int off = 8; off >= 1; off >>= 1) {
    s  += __shfl_xor(s, off);
    s2 += __shfl_xor(s2, off);
  }
  const float mean = s * 0.00390625f;
  const float inv  = rsqrtf(s2 * 0.00390625f - mean * mean + 1e-5f);
  #pragma unroll
  for (int j = 0; j < 4; ++j) {
    const int e = 4 * l + 64 * j;
    const f32x4 gv = *(const f32x4*)(g + e);
    const f32x4 bv = *(const f32x4*)(b + e);
    const f32x4 sc = *(const f32x4*)(scale + spos * 256 + e);
    const f32x4 sh = *(const f32x4*)(shift + spos * 256 + e);
    u16x4 o;
    #pragma unroll
    for (int i = 0; i < 4; ++i) {
      float ln = (v[j][i] - mean) * inv * gv[i] + bv[i];
      ln = ln * (sc[i] + 1.0f) + sh[i];
      o[i] = f2b(ln);
    }
    *(u16x4*)(out + tb + e) = o;
  }
}

// ---------------------------------------------------------------------------
// Fused QKV GEMM: A(65536x256) bf16 @ {WqT,WkT,WvT}.
// Flat grid 3072, XCD-aware decode: all 6 blocks sharing an A-tile (same y)
// carry the same id%8 -> same XCD L2.
// q,k stored head-major [w][h][t][32]; v stored key-permuted for the
// swapped-QK attention.
// ---------------------------------------------------------------------------
__global__ __launch_bounds__(256) void gemm_qkv(
    const u16* __restrict__ A, const u16* __restrict__ wt,
    const float* __restrict__ bq, const float* __restrict__ bk,
    const float* __restrict__ bv, u16* __restrict__ qo,
    u16* __restrict__ ko, u16* __restrict__ vo)
{
  __shared__ __align__(16) u16 Alds[128][72];
  __shared__ __align__(16) u16 Blds[128][72];
  const int bid = blockIdx.x;
  const int xcd = bid & 7, rr = bid >> 3;
  const int xx = rr % 6;                   // weight*2 + n-half
  const int yy = (rr / 6) * 8 + xcd;       // m-block 0..511
  const int wsel = xx >> 1;
  const int m0 = yy * 128;
  const int n0 = (xx & 1) * 128;
  const u16* BT = wt + (size_t)wsel * 65536;
  const int t = threadIdx.x;
  const int wave = t >> 6, lane = t & 63;
  const int wm = (wave & 1) * 64, wn = (wave >> 1) * 64;
  const int lrow = lane & 15, lk = (lane >> 4) * 8;

  f32x4 acc[4][4];
  #pragma unroll
  for (int i = 0; i < 4; ++i)
    #pragma unroll
    for (int j = 0; j < 4; ++j)
      acc[i][j] = f32x4{0.f, 0.f, 0.f, 0.f};

  for (int k0 = 0; k0 < 256; k0 += 64) {
    #pragma unroll
    for (int i = 0; i < 4; ++i) {
      const int c = i * 256 + t;
      const int row = c >> 3, col = (c & 7) * 8;
      *(i32x4*)(&Alds[row][col]) = *(const i32x4*)(A  + (size_t)(m0 + row) * 256 + k0 + col);
      *(i32x4*)(&Blds[row][col]) = *(const i32x4*)(BT + (size_t)(n0 + row) * 256 + k0 + col);
    }
    __syncthreads();
    #pragma unroll
    for (int kk = 0; kk < 64; kk += 32) {
      s16x8 af[4], bf[4];
      #pragma unroll
      for (int mt = 0; mt < 4; ++mt) af[mt] = *(const s16x8*)(&Alds[wm + mt*16 + lrow][kk + lk]);
      #pragma unroll
      for (int nt = 0; nt < 4; ++nt) bf[nt] = *(const s16x8*)(&Blds[wn + nt*16 + lrow][kk + lk]);
      #pragma unroll
      for (int mt = 0; mt < 4; ++mt)
        #pragma unroll
        for (int nt = 0; nt < 4; ++nt)
          acc[mt][nt] = __builtin_amdgcn_mfma_f32_16x16x32_bf16(af[mt], bf[nt], acc[mt][nt], 0, 0, 0);
    }
    __syncthreads();
  }

  const float* bias = (wsel == 0) ? bq : (wsel == 1) ? bk : bv;
  u16* qko = (wsel == 0) ? qo : ko;
  #pragma unroll
  for (int mt = 0; mt < 4; ++mt) {
    const int mb = m0 + wm + mt*16 + (lane >> 4) * 4;
    const int w = mb >> 8, tok = mb & 255;
    #pragma unroll
    for (int nt = 0; nt < 4; ++nt) {
      const int n = n0 + wn + nt*16 + lrow;
      const int h = n >> 5, d = n & 31;
      const float bv_ = bias[n];
      if (wsel < 2) {
        #pragma unroll
        for (int r = 0; r < 4; ++r)
          qko[(size_t)w * 65536 + h * 8192 + (tok + r) * 32 + d] = f2b(acc[mt][nt][r] + bv_);
      } else {
        // tok % 4 == 0 -> the 4 keys tok..tok+3 are contiguous at this addr.
        u16x4 pk;
        #pragma unroll
        for (int r = 0; r < 4; ++r) pk[r] = f2b(acc[mt][nt][r] + bv_);
        const int vaddr = ((tok >> 5) << 10) + (((tok >> 2) & 3) << 8)
                        + d * 8 + (((tok >> 4) & 1) << 2);
        *(u16x4*)(vo + (size_t)w * 65536 + h * 8192 + vaddr) = pk;
      }
    }
  }
}

// ---------------------------------------------------------------------------
// Fused tail (R5 staged structure + XH XOR-swizzle):
//   x1 = x + gam*(A@WoT + bo)  (bf16 in regs); LN2 in-block;
//   H = silu(xn@W1T); out = b2f(x1) + gml*(H@W2T).
// Weight panels staged in Blds[256][72] (proven conflict-free layout).
// XH[64][256], index n ^= (row&14)<<2  (16B-block XOR):
//   scalar LN/silu writes -> 32 banks, 2 lanes/bank (free);
//   b128 reads -> 2-way per 16-lane quarter (free).
// grid 1024 x 512 thr (8 waves: 2m x 4n). LDS ~72 KB -> 2 blocks/CU.
// ---------------------------------------------------------------------------
__global__ __launch_bounds__(512) void gemm_tail(
    const u16* __restrict__ A, const u16* __restrict__ WoT,
    const u16* __restrict__ W1T, const u16* __restrict__ W2T,
    const float* __restrict__ bo, const float* __restrict__ x,
    const float* __restrict__ gam, const float* __restrict__ lg2,
    const float* __restrict__ lb2, const float* __restrict__ gml,
    float* __restrict__ outx)
{
  __shared__ __align__(16) u16 Blds[256][72];   // weight panel 256n x 64k (+8)
  __shared__ __align__(16) u16 XH[64][256];     // xn, then H (XOR-swizzled)
  __shared__ float LNp[4][64][2];
  __shared__ float LNm[64][2];
  const int m0 = blockIdx.x * 64;
  const int t = threadIdx.x;
  const int wave = t >> 6, lane = t & 63;
  const int wm = (wave & 1) * 32, wn = (wave >> 1) * 64;
  const int lrow = lane & 15, lk = (lane >> 4) * 8;
  const int quad = lane >> 4, col = lane & 15;

  f32x4 acc[2][4];
  #pragma unroll
  for (int i = 0; i < 2; ++i)
    #pragma unroll
    for (int j = 0; j < 4; ++j) acc[i][j] = f32x4{0.f,0.f,0.f,0.f};

  // ================= phase A: acc = A @ WoT =================
  for (int p = 0; p < 4; ++p) {
    const int k0 = p * 64;
    #pragma unroll
    for (int i = 0; i < 4; ++i) {
      const int bb = i * 8192 + t * 16;
      const int n = bb >> 7, kk = (bb & 127) >> 1;
      *(i32x4*)(&Blds[n][kk]) = *(const i32x4*)(WoT + (size_t)n * 256 + k0 + kk);
    }
    __syncthreads();
    #pragma unroll
    for (int kk = 0; kk < 64; kk += 32) {
      s16x8 af[2], bf[4];
      #pragma unroll
      for (int mt = 0; mt < 2; ++mt)
        af[mt] = *(const s16x8*)(A + (size_t)(m0 + wm + mt*16 + lrow) * 256 + k0 + kk + lk);
      #pragma unroll
      for (int nt = 0; nt < 4; ++nt)
        bf[nt] = *(const s16x8*)(&Blds[wn + nt*16 + lrow][kk + lk]);
      #pragma unroll
      for (int mt = 0; mt < 2; ++mt)
        #pragma unroll
        for (int nt = 0; nt < 4; ++nt)
          acc[mt][nt] = __builtin_amdgcn_mfma_f32_16x16x32_bf16(af[mt], bf[nt], acc[mt][nt], 0, 0, 0);
    }
    __syncthreads();
  }

  // ---- epilogue A: x1 (bf16 in regs) + LN partial sums
  unsigned int x1p[2][4][2];
  float s[2][4], s2[2][4];
  #pragma unroll
  for (int mt = 0; mt < 2; ++mt)
    #pragma unroll
    for (int r = 0; r < 4; ++r) { s[mt][r] = 0.f; s2[mt][r] = 0.f; }

  #pragma unroll
  for (int mt = 0; mt < 2; ++mt) {
    const int mb = m0 + wm + mt*16 + quad*4;
    #pragma unroll
    for (int nt = 0; nt < 4; ++nt) {
      const int n = wn + nt*16 + col;
      const float bon = bo[n], gn = gam[n];
      float v[4];
      #pragma unroll
      for (int r = 0; r < 4; ++r)
        v[r] = x[(size_t)(mb + r) * 256 + n] + gn * (acc[mt][nt][r] + bon);
      const unsigned int p0 = cvt_pk(v[0], v[1]);
      const unsigned int p1 = cvt_pk(v[2], v[3]);
      x1p[mt][nt][0] = p0;
      x1p[mt][nt][1] = p1;
      const float r0 = b2f((u16)(p0 & 0xffffu)), r1 = b2f((u16)(p0 >> 16));
      const float r2 = b2f((u16)(p1 & 0xffffu)), r3 = b2f((u16)(p1 >> 16));
      s[mt][0] += r0; s2[mt][0] += r0 * r0;
      s[mt][1] += r1; s2[mt][1] += r1 * r1;
      s[mt][2] += r2; s2[mt][2] += r2 * r2;
      s[mt][3] += r3; s2[mt][3] += r3 * r3;
    }
  }
  // intra-wave reduce over the 16 col lanes
  #pragma unroll
  for (int off = 1; off <= 8; off <<= 1) {
    #pragma unroll
    for (int mt = 0; mt < 2; ++mt)
      #pragma unroll
      for (int r = 0; r < 4; ++r) {
        s[mt][r]  += __shfl_xor(s[mt][r],  off);
        s2[mt][r] += __shfl_xor(s2[mt][r], off);
      }
  }
  if (col == 0) {
    #pragma unroll
    for (int mt = 0; mt < 2; ++mt)
      #pragma unroll
      for (int r = 0; r < 4; ++r) {
        const int row = wm + mt*16 + quad*4 + r;
        LNp[wave >> 1][row][0] = s[mt][r];
        LNp[wave >> 1][row][1] = s2[mt][r];
      }
  }
  __syncthreads();
  if (t < 64) {
    const float ss  = LNp[0][t][0] + LNp[1][t][0] + LNp[2][t][0] + LNp[3][t][0];
    const float ss2 = LNp[0][t][1] + LNp[1][t][1] + LNp[2][t][1] + LNp[3][t][1];
    const float mean = ss * 0.00390625f;
    LNm[t][0] = mean;
    LNm[t][1] = rsqrtf(ss2 * 0.00390625f - mean * mean + 1e-5f);
  }
  __syncthreads();
  // xn -> XH (swizzled)
  #pragma unroll
  for (int mt = 0; mt < 2; ++mt) {
    #pragma unroll
    for (int nt = 0; nt < 4; ++nt) {
      const int n = wn + nt*16 + col;
      const float gg = lg2[n], bb_ = lb2[n];
      #pragma unroll
      for (int rr = 0; rr < 2; ++rr) {
        const unsigned int pk = x1p[mt][nt][rr];
        #pragma unroll
        for (int h2 = 0; h2 < 2; ++h2) {
          const int r = rr * 2 + h2;
          const int row = wm + mt*16 + quad*4 + r;
          const float rv = b2f((u16)(h2 ? (pk >> 16) : (pk & 0xffffu)));
          const float xn = (rv - LNm[row][0]) * LNm[row][1] * gg + bb_;
          XH[row][n ^ ((row & 14) << 2)] = f2b(xn);
        }
      }
    }
  }
  __syncthreads();

  // ================= phase B: acc = XH @ W1T =================
  #pragma unroll
  for (int i = 0; i < 2; ++i)
    #pragma unroll
    for (int j = 0; j < 4; ++j) acc[i][j] = f32x4{0.f,0.f,0.f,0.f};
  for (int p = 0; p < 4; ++p) {
    const int k0 = p * 64;
    #pragma unroll
    for (int i = 0; i < 4; ++i) {
      const int bb = i * 8192 + t * 16;
      const int n = bb >> 7, kk = (bb & 127) >> 1;
      *(i32x4*)(&Blds[n][kk]) = *(const i32x4*)(W1T + (size_t)n * 256 + k0 + kk);
    }
    __syncthreads();
    #pragma unroll
    for (int kk = 0; kk < 64; kk += 32) {
      s16x8 af[2], bf[4];
      #pragma unroll
      for (int mt = 0; mt < 2; ++mt) {
        const int row = wm + mt*16 + lrow;
        af[mt] = *(const s16x8*)(&XH[row][(k0 + kk + lk) ^ ((row & 14) << 2)]);
      }
      #pragma unroll
      for (int nt = 0; nt < 4; ++nt)
        bf[nt] = *(const s16x8*)(&Blds[wn + nt*16 + lrow][kk + lk]);
      #pragma unroll
      for (int mt = 0; mt < 2; ++mt)
        #pragma unroll
        for (int nt = 0; nt < 4; ++nt)
          acc[mt][nt] = __builtin_amdgcn_mfma_f32_16x16x32_bf16(af[mt], bf[nt], acc[mt][nt], 0, 0, 0);
    }
    __syncthreads();
  }
  // silu -> H overwrites XH (swizzled)
  #pragma unroll
  for (int mt = 0; mt < 2; ++mt)
    #pragma unroll
    for (int nt = 0; nt < 4; ++nt)
      #pragma unroll
      for (int r = 0; r < 4; ++r) {
        const float y = acc[mt][nt][r];
        const float hsig = __builtin_amdgcn_rcpf(1.0f + __builtin_amdgcn_exp2f(-1.442695041f * y));
        const int row = wm + mt*16 + quad*4 + r;
        const int n = wn + nt*16 + col;
        XH[row][n ^ ((row & 14) << 2)] = f2b(y * hsig);
        acc[mt][nt][r] = 0.0f;
      }
  __syncthreads();

  // ================= phase C: acc = H @ W2T =================
  for (int p = 0; p < 4; ++p) {
    const int k0 = p * 64;
    #pragma unroll
    for (int i = 0; i < 4; ++i) {
      const int bb = i * 8192 + t * 16;
      const int n = bb >> 7, kk = (bb & 127) >> 1;
      *(i32x4*)(&Blds[n][kk]) = *(const i32x4*)(W2T + (size_t)n * 256 + k0 + kk);
    }
    __syncthreads();
    #pragma unroll
    for (int kk = 0; kk < 64; kk += 32) {
      s16x8 af[2], bf[4];
      #pragma unroll
      for (int mt = 0; mt < 2; ++mt) {
        const int row = wm + mt*16 + lrow;
        af[mt] = *(const s16x8*)(&XH[row][(k0 + kk + lk) ^ ((row & 14) << 2)]);
      }
      #pragma unroll
      for (int nt = 0; nt < 4; ++nt)
        bf[nt] = *(const s16x8*)(&Blds[wn + nt*16 + lrow][kk + lk]);
      #pragma unroll
      for (int mt = 0; mt < 2; ++mt)
        #pragma unroll
        for (int nt = 0; nt < 4; ++nt)
          acc[mt][nt] = __builtin_amdgcn_mfma_f32_16x16x32_bf16(af[mt], bf[nt], acc[mt][nt], 0, 0, 0);
    }
    __syncthreads();
  }

  // ---- epilogue C: out = b2f(x1) + gml[n]*acc
  #pragma unroll
  for (int mt = 0; mt < 2; ++mt) {
    const int mb = m0 + wm + mt*16 + quad*4;
    #pragma unroll
    for (int nt = 0; nt < 4; ++nt) {
      const int n = wn + nt*16 + col;
      const float gn = gml[n];
      #pragma unroll
      for (int rr = 0; rr < 2; ++rr) {
        const unsigned int pk = x1p[mt][nt][rr];
        outx[(size_t)(mb + rr*2    ) * 256 + n] = b2f((u16)(pk & 0xffffu)) + gn * acc[mt][nt][rr*2];
        outx[(size_t)(mb + rr*2 + 1) * 256 + n] = b2f((u16)(pk >> 16))     + gn * acc[mt][nt][rr*2 + 1];
      }
    }
  }
}

// ---------------------------------------------------------------------------
// Attention v6: flat grid 4096 x 512 thr (8 waves, 16 queries each),
// XCD-aware decode: the 2 blocks sharing a (w,h) K/V slice -> same XCD.
// K+V (32 KB) staged once per block into LDS; swapped-QK register softmax;
// P feeds PV MFMA directly from registers (V key-permuted by gemm_qkv).
// ---------------------------------------------------------------------------
__global__ __launch_bounds__(512) void attn256(
    const u16* __restrict__ q, const u16* __restrict__ k,
    const u16* __restrict__ vt, const float* __restrict__ fbias,
    u16* __restrict__ out)
{
  __shared__ __align__(16) u16 KV[16384];     // K bytes [0,16K) | V bytes [16K,32K)
  __shared__ __align__(16) u16 OB[8][16][40];
  const int bid = blockIdx.x;
  const int xcd = bid & 7, rr = bid >> 3;
  const int q0 = (rr & 1) * 128;
  const int s_ = (rr >> 1) * 8 + xcd;        // 0..2047
  const int h = s_ & 7, w = s_ >> 3;
  const int t = threadIdx.x;
  const int wave = t >> 6, lane = t & 63;
  const int col = lane & 15, quad = lane >> 4;
  const size_t hb = (size_t)w * 65536 + (size_t)h * 8192;
  const int qr0 = q0 + wave * 16;
  const float sc2 = 0.25508586f;  // (1/sqrt(32)) * log2(e)

  // ---- stage K and V (64B per thread each), linear copy
  {
    const char* kg = (const char*)(k + hb);
    const char* vg = (const char*)(vt + hb);
    const i32x4 r0 = *(const i32x4*)(kg + t * 16);
    const i32x4 r1 = *(const i32x4*)(kg + 8192 + t * 16);
    const i32x4 r2 = *(const i32x4*)(vg + t * 16);
    const i32x4 r3 = *(const i32x4*)(vg + 8192 + t * 16);
    char* lb = (char*)KV;
    *(i32x4*)(lb + t * 16)         = r0;
    *(i32x4*)(lb + 8192 + t * 16)  = r1;
    *(i32x4*)(lb + 16384 + t * 16) = r2;
    *(i32x4*)(lb + 24576 + t * 16) = r3;
  }

  // Q fragment + mask bias (global; overlap with stage)
  const s16x8 af = *(const s16x8*)(q + hb + (qr0 + col) * 32 + quad * 8);
  const float* fbb = fbias + w * 256 + quad * 4;
  __syncthreads();

  // ---- QK^T swapped (K from LDS): acc[tl][r] = S[key=tl*16+quad*4+r][q=col]
  f32x4 acc[16];
  #pragma unroll
  for (int tl = 0; tl < 16; ++tl) {
    const s16x8 kf = *(const s16x8*)(KV + (tl * 16 + col) * 32 + quad * 8);
    acc[tl] = __builtin_amdgcn_mfma_f32_16x16x32_bf16(kf, af, f32x4{0.f,0.f,0.f,0.f}, 0, 0, 0);
  }

  // ---- scale + mask bias
  #pragma unroll
  for (int tl = 0; tl < 16; ++tl) {
    const f32x4 fb = *(const f32x4*)(fbb + tl * 16);
    #pragma unroll
    for (int r = 0; r < 4; ++r)
      acc[tl][r] = fmaf(acc[tl][r], sc2, fb[r]);
  }

  // ---- lane-local max over 64 keys, then cross-quad (2 shuffles)
  f32x4 m4 = acc[0];
  #pragma unroll
  for (int tl = 1; tl < 16; ++tl)
    #pragma unroll
    for (int r = 0; r < 4; ++r)
      m4[r] = fmaxf(m4[r], acc[tl][r]);
  float mx = fmaxf(fmaxf(m4[0], m4[1]), fmaxf(m4[2], m4[3]));
  mx = fmaxf(mx, __shfl_xor(mx, 16));
  mx = fmaxf(mx, __shfl_xor(mx, 32));

  // ---- exp2 + lane-local sum, then cross-quad (2 shuffles)
  f32x4 s4 = {0.f, 0.f, 0.f, 0.f};
  #pragma unroll
  for (int tl = 0; tl < 16; ++tl) {
    #pragma unroll
    for (int r = 0; r < 4; ++r) {
      const float e = __builtin_amdgcn_exp2f(acc[tl][r] - mx);
      acc[tl][r] = e;
      s4[r] += e;
    }
  }
  float sum = (s4[0] + s4[1]) + (s4[2] + s4[3]);
  sum += __shfl_xor(sum, 16);
  sum += __shfl_xor(sum, 32);
  const float inv = __builtin_amdgcn_rcpf(sum);

  // ---- PV from registers (V from LDS, pre-permuted)
  f32x4 o0 = {0.f,0.f,0.f,0.f}, o1 = {0.f,0.f,0.f,0.f};
  const u16* vl = KV + 8192;
  #pragma unroll
  for (int s = 0; s < 8; ++s) {
    i32x4 pi;
    pi[0] = (int)cvt_pk(acc[2*s][0],     acc[2*s][1]);
    pi[1] = (int)cvt_pk(acc[2*s][2],     acc[2*s][3]);
    pi[2] = (int)cvt_pk(acc[2*s + 1][0], acc[2*s + 1][1]);
    pi[3] = (int)cvt_pk(acc[2*s + 1][2], acc[2*s + 1][3]);
    const s16x8 pf = *(const s16x8*)&pi;
    const s16x8 vf0 = *(const s16x8*)(vl + s * 1024 + quad * 256 + col * 8);
    const s16x8 vf1 = *(const s16x8*)(vl + s * 1024 + quad * 256 + col * 8 + 128);
    o0 = __builtin_amdgcn_mfma_f32_16x16x32_bf16(pf, vf0, o0, 0, 0, 0);
    o1 = __builtin_amdgcn_mfma_f32_16x16x32_bf16(pf, vf1, o1, 0, 0, 0);
  }

  // ---- 1/sum for output rows q = quad*4+r lives at lane (*, quad*4+r)
  f32x4 invr;
  #pragma unroll
  for (int r = 0; r < 4; ++r) invr[r] = __shfl(inv, quad * 4 + r);

  // ---- bounce O through LDS for 16B/lane stores (wave-private slab)
  #pragma unroll
  for (int r = 0; r < 4; ++r) {
    OB[wave][quad * 4 + r][col]      = f2b(o0[r] * invr[r]);
    OB[wave][quad * 4 + r][col + 16] = f2b(o1[r] * invr[r]);
  }
  const s16x8 ov = *(const s16x8*)(&OB[wave][col][quad * 8]);
  *(s16x8*)(out + (size_t)w * 65536 + (size_t)(qr0 + col) * 256 + h * 32 + quad * 8) = ov;
}

// ---------------------------------------------------------------------------
// mask_update + attention bias precompute. grid 256 x 256.
// ---------------------------------------------------------------------------
__global__ __launch_bounds__(256) void maskup(const int* __restrict__ mask,
                                              float* __restrict__ out,
                                              float* __restrict__ fbias)
{
  __shared__ int wall[4];
  const int w = blockIdx.x, t = threadIdx.x;
  const int v = (mask[w * 256 + t] != 0) ? 1 : 0;
  const int a = __all(v);
  if ((t & 63) == 0) wall[t >> 6] = a;
  __syncthreads();
  const int allw = wall[0] & wall[1] & wall[2] & wall[3];
  out[w * 256 + t] = (v & allw) ? 1.0f : 0.0f;
  fbias[w * 256 + t] = v ? 0.0f : -1.0e9f;
}

// ---------------------------------------------------------------------------
extern "C" void kernel_launch(void* const* d_in, const int* in_sizes, int n_in,
                              void* d_out, int out_size, void* d_ws, size_t ws_size,
                              hipStream_t stream)
{
  (void)in_sizes; (void)n_in; (void)out_size; (void)ws_size;
  const float* x    = (const float*)d_in[0];
  const int*   mask = (const int*)d_in[1];
  const float* pos  = (const float*)d_in[2];
  const float* Wemb = (const float*)d_in[3];
  const float* bemb = (const float*)d_in[4];
  const float* ln1g = (const float*)d_in[5];
  const float* ln1b = (const float*)d_in[6];
  const float* Wq   = (const float*)d_in[7];
  const float* bq   = (const float*)d_in[8];
  const float* Wk   = (const float*)d_in[9];
  const float* bk   = (const float*)d_in[10];
  const float* Wv   = (const float*)d_in[11];
  const float* bv   = (const float*)d_in[12];
  const float* Wo   = (const float*)d_in[13];
  const float* bo   = (const float*)d_in[14];
  const float* ln2g = (const float*)d_in[15];
  const float* ln2b = (const float*)d_in[16];
  const float* W1   = (const float*)d_in[17];
  const float* W2   = (const float*)d_in[18];
  const float* gam  = (const float*)d_in[19];
  const float* gml  = (const float*)d_in[20];

  char* ws = (char*)d_ws;
  float* shift = (float*)ws;                       // 256 KB
  float* scale = (float*)(ws + (256 << 10));       // 256 KB
  u16*   wt    = (u16*)(ws + (512 << 10));         // 768 KB (6 x 256x256)
  float* fbias = (float*)(ws + (1280 << 10));      // 256 KB
  u16*   b0    = (u16*)(ws + ((size_t)2  << 20));  // xm   -> attn_out
  u16*   b1    = (u16*)(ws + ((size_t)34 << 20));  // q^
  u16*   b2    = (u16*)(ws + ((size_t)66 << 20));  // k^
  u16*   b3    = (u16*)(ws + ((size_t)98 << 20));  // V~
  float* outx  = (float*)d_out;
  float* outm  = outx + 16777216;

  const u16* WoT = wt + 3 * 65536;
  const u16* W1T = wt + 4 * 65536;
  const u16* W2T = wt + 5 * 65536;

  transpose6<<<dim3(6, 16), 256, 0, stream>>>(Wq, Wk, Wv, Wo, W1, W2, wt);
  film_kernel<<<dim3(256, 8), 256, 0, stream>>>(pos, Wemb, bemb, shift, scale);
  maskup<<<256, 256, 0, stream>>>(mask, outm, fbias);
  ln_kernel<<<4096, 256, 0, stream>>>(x, shift, scale, ln1g, ln1b, b0);
  gemm_qkv<<<3072, 256, 0, stream>>>(b0, wt, bq, bk, bv, b1, b2, b3);
  attn256<<<4096, 512, 0, stream>>>(b1, b2, b3, fbias, b0);
  // fused tail: Wo-residual + LN2 + MLP, single pass over the activations
  gemm_tail<<<1024, 512, 0, stream>>>(b0, WoT, W1T, W2T, bo, x, gam,
                                      ln2g, ln2b, gml, outx);
}

// Round 8
// 333.175 us; speedup vs baseline: 1.1672x; 1.0367x over previous
//
#include <hip/hip_runtime.h>
#include <cstddef>
#include <cstdint>

typedef unsigned short u16;
typedef short s16x8 __attribute__((ext_vector_type(8)));
typedef float f32x4 __attribute__((ext_vector_type(4)));
typedef int   i32x4 __attribute__((ext_vector_type(4)));
typedef u16   u16x4 __attribute__((ext_vector_type(4)));

__device__ __forceinline__ float b2f(u16 u) {
  union { unsigned int i; float f; } v; v.i = ((unsigned int)u) << 16; return v.f;
}
__device__ __forceinline__ u16 f2b(float f) {
  union { float f; unsigned int i; } v; v.f = f;
  unsigned int r = v.i + 0x7fffu + ((v.i >> 16) & 1u);
  return (u16)(r >> 16);
}
// pack 2 fp32 -> 2 bf16 (RNE) in one instruction; low 16 bits = a.
__device__ __forceinline__ unsigned int cvt_pk(float a, float b) {
  unsigned int r;
  asm("v_cvt_pk_bf16_f32 %0, %1, %2" : "=v"(r) : "v"(a), "v"(b));
  return r;
}

// ---------------------------------------------------------------------------
// Transpose+cast 6 fp32 weight matrices (256x256) -> bf16 WT[n][k].
// grid (6,16) x 256 thr; 64x64 tile per block.
// ---------------------------------------------------------------------------
__global__ __launch_bounds__(256) void transpose6(
    const float* __restrict__ w0, const float* __restrict__ w1,
    const float* __restrict__ w2, const float* __restrict__ w3,
    const float* __restrict__ w4, const float* __restrict__ w5,
    u16* __restrict__ wt)
{
  __shared__ u16 T[64][66];
  const float* src;
  switch (blockIdx.x) {
    case 0: src = w0; break; case 1: src = w1; break;
    case 2: src = w2; break; case 3: src = w3; break;
    case 4: src = w4; break; default: src = w5; break;
  }
  u16* dst = wt + (size_t)blockIdx.x * 65536;
  const int tr = (blockIdx.y & 3) * 64;
  const int tc = (blockIdx.y >> 2) * 64;
  const int lane = threadIdx.x & 63, grp = threadIdx.x >> 6;
  #pragma unroll
  for (int i = 0; i < 16; ++i) {
    const int r = grp + i * 4;
    T[lane][r] = f2b(src[(size_t)(tr + r) * 256 + tc + lane]);
  }
  __syncthreads();
  #pragma unroll
  for (int i = 0; i < 16; ++i) {
    const int j = grp + i * 4;
    dst[(size_t)(tc + j) * 256 + tr + lane] = T[j][lane];
  }
}

// ---------------------------------------------------------------------------
// FiLM precompute (fp32): emb = pos(256x256) @ W_emb(256x512) + b_emb
// grid (256,8) x 256 thr.
// ---------------------------------------------------------------------------
__global__ __launch_bounds__(256) void film_kernel(
    const float* __restrict__ pos, const float* __restrict__ Wemb,
    const float* __restrict__ bemb, float* __restrict__ shift,
    float* __restrict__ scale)
{
  __shared__ float prow[256];
  __shared__ float psum[4][64];
  const int s = blockIdx.x, t = threadIdx.x;
  const int ks = t >> 6, cl = t & 63;
  const int c = blockIdx.y * 64 + cl;
  prow[t] = pos[s * 256 + t];
  __syncthreads();
  float acc = 0.f;
  #pragma unroll 8
  for (int kk = ks * 64; kk < ks * 64 + 64; ++kk)
    acc = fmaf(prow[kk], Wemb[kk * 512 + c], acc);
  psum[ks][cl] = acc;
  __syncthreads();
  if (t < 64) {
    const int cc = blockIdx.y * 64 + t;
    const float v = psum[0][t] + psum[1][t] + psum[2][t] + psum[3][t] + bemb[cc];
    if (cc < 256) shift[s * 256 + cc] = v;
    else          scale[s * 256 + cc - 256] = v;
  }
}

// ---------------------------------------------------------------------------
// LayerNorm (fp32 + FiLM): token owned by a 16-lane group. grid 4096 x 256.
// ---------------------------------------------------------------------------
__global__ __launch_bounds__(256) void ln_kernel(
    const float* __restrict__ xf,
    const float* __restrict__ shift, const float* __restrict__ scale,
    const float* __restrict__ g, const float* __restrict__ b,
    u16* __restrict__ out)
{
  const int lane = threadIdx.x & 63;
  const int l = lane & 15, grp = lane >> 4;
  const int token = blockIdx.x * 16 + (threadIdx.x >> 6) * 4 + grp;
  const size_t tb = (size_t)token * 256;
  const int spos = token & 255;

  f32x4 v[4];
  #pragma unroll
  for (int j = 0; j < 4; ++j) v[j] = *(const f32x4*)(xf + tb + 4 * l + 64 * j);
  float s = 0.f, s2 = 0.f;
  #pragma unroll
  for (int j = 0; j < 4; ++j)
    #pragma unroll
    for (int i = 0; i < 4; ++i) { s += v[j][i]; s2 += v[j][i] * v[j][i]; }
  #pragma unroll
  for (int off = 8; off >= 1; off >>= 1) {
    s  += __shfl_xor(s, off);
    s2 += __shfl_xor(s2, off);
  }
  const float mean = s * 0.00390625f;
  const float inv  = rsqrtf(s2 * 0.00390625f - mean * mean + 1e-5f);
  #pragma unroll
  for (int j = 0; j < 4; ++j) {
    const int e = 4 * l + 64 * j;
    const f32x4 gv = *(const f32x4*)(g + e);
    const f32x4 bv = *(const f32x4*)(b + e);
    const f32x4 sc = *(const f32x4*)(scale + spos * 256 + e);
    const f32x4 sh = *(const f32x4*)(shift + spos * 256 + e);
    u16x4 o;
    #pragma unroll
    for (int i = 0; i < 4; ++i) {
      float ln = (v[j][i] - mean) * inv * gv[i] + bv[i];
      ln = ln * (sc[i] + 1.0f) + sh[i];
      o[i] = f2b(ln);
    }
    *(u16x4*)(out + tb + e) = o;
  }
}

// ---------------------------------------------------------------------------
// Fused QKV GEMM, register-pipelined staging: panel p+1 global loads are in
// flight while panel p computes -> only ds_write+MFMA between barriers.
// Flat grid 3072, XCD-aware decode (6 A-tile sharers on one XCD).
// q,k head-major [w][h][t][32]; v key-permuted for swapped-QK attention.
// ---------------------------------------------------------------------------
__global__ __launch_bounds__(256) void gemm_qkv(
    const u16* __restrict__ A, const u16* __restrict__ wt,
    const float* __restrict__ bq, const float* __restrict__ bk,
    const float* __restrict__ bv, u16* __restrict__ qo,
    u16* __restrict__ ko, u16* __restrict__ vo)
{
  __shared__ __align__(16) u16 Alds[128][72];
  __shared__ __align__(16) u16 Blds[128][72];
  const int bid = blockIdx.x;
  const int xcd = bid & 7, rr = bid >> 3;
  const int xx = rr % 6;                   // weight*2 + n-half
  const int yy = (rr / 6) * 8 + xcd;       // m-block 0..511
  const int wsel = xx >> 1;
  const int m0 = yy * 128;
  const int n0 = (xx & 1) * 128;
  const u16* BT = wt + (size_t)wsel * 65536;
  const int t = threadIdx.x;
  const int wave = t >> 6, lane = t & 63;
  const int wm = (wave & 1) * 64, wn = (wave >> 1) * 64;
  const int lrow = lane & 15, lk = (lane >> 4) * 8;
  const int brow = t >> 3, bcol = (t & 7) * 8;

  f32x4 acc[4][4];
  #pragma unroll
  for (int i = 0; i < 4; ++i)
    #pragma unroll
    for (int j = 0; j < 4; ++j)
      acc[i][j] = f32x4{0.f, 0.f, 0.f, 0.f};

  i32x4 ra[4], rb[4];
#define QK_LOAD(p) { \
    _Pragma("unroll") \
    for (int i_ = 0; i_ < 4; ++i_) { \
      ra[i_] = *(const i32x4*)(A  + (size_t)(m0 + i_*32 + brow) * 256 + (p)*64 + bcol); \
      rb[i_] = *(const i32x4*)(BT + (size_t)(n0 + i_*32 + brow) * 256 + (p)*64 + bcol); } }
#define QK_STORE() { \
    _Pragma("unroll") \
    for (int i_ = 0; i_ < 4; ++i_) { \
      *(i32x4*)(&Alds[i_*32 + brow][bcol]) = ra[i_]; \
      *(i32x4*)(&Blds[i_*32 + brow][bcol]) = rb[i_]; } }
#define QK_COMP(p) { \
    _Pragma("unroll") \
    for (int kk = 0; kk < 64; kk += 32) { \
      s16x8 af[4], bf[4]; \
      _Pragma("unroll") \
      for (int mt = 0; mt < 4; ++mt) af[mt] = *(const s16x8*)(&Alds[wm + mt*16 + lrow][kk + lk]); \
      _Pragma("unroll") \
      for (int nt = 0; nt < 4; ++nt) bf[nt] = *(const s16x8*)(&Blds[wn + nt*16 + lrow][kk + lk]); \
      _Pragma("unroll") \
      for (int mt = 0; mt < 4; ++mt) \
        _Pragma("unroll") \
        for (int nt = 0; nt < 4; ++nt) \
          acc[mt][nt] = __builtin_amdgcn_mfma_f32_16x16x32_bf16(af[mt], bf[nt], acc[mt][nt], 0, 0, 0); } }

  QK_LOAD(0);
  QK_STORE();
  QK_LOAD(1);
  __syncthreads();
  QK_COMP(0);
  __syncthreads();
  QK_STORE();
  QK_LOAD(2);
  __syncthreads();
  QK_COMP(1);
  __syncthreads();
  QK_STORE();
  QK_LOAD(3);
  __syncthreads();
  QK_COMP(2);
  __syncthreads();
  QK_STORE();
  __syncthreads();
  QK_COMP(3);

  const float* bias = (wsel == 0) ? bq : (wsel == 1) ? bk : bv;
  u16* qko = (wsel == 0) ? qo : ko;
  #pragma unroll
  for (int mt = 0; mt < 4; ++mt) {
    const int mb = m0 + wm + mt*16 + (lane >> 4) * 4;
    const int w = mb >> 8, tok = mb & 255;
    #pragma unroll
    for (int nt = 0; nt < 4; ++nt) {
      const int n = n0 + wn + nt*16 + lrow;
      const int h = n >> 5, d = n & 31;
      const float bv_ = bias[n];
      if (wsel < 2) {
        #pragma unroll
        for (int r = 0; r < 4; ++r)
          qko[(size_t)w * 65536 + h * 8192 + (tok + r) * 32 + d] = f2b(acc[mt][nt][r] + bv_);
      } else {
        // tok % 4 == 0 -> the 4 keys tok..tok+3 are contiguous at this addr.
        u16x4 pk;
        #pragma unroll
        for (int r = 0; r < 4; ++r) pk[r] = f2b(acc[mt][nt][r] + bv_);
        const int vaddr = ((tok >> 5) << 10) + (((tok >> 2) & 3) << 8)
                        + d * 8 + (((tok >> 4) & 1) << 2);
        *(u16x4*)(vo + (size_t)w * 65536 + h * 8192 + vaddr) = pk;
      }
    }
  }
#undef QK_LOAD
#undef QK_STORE
#undef QK_COMP
}

// ---------------------------------------------------------------------------
// Fused tail, register-pipelined: weight panel p+1 is loaded to VGPRs while
// panel p computes; cross-phase prefetch keeps the pipe full through LN/silu.
//   x1 = x + gam*(A@WoT + bo)  (bf16 in regs); LN2 in-block;
//   H = silu(xn@W1T); out = b2f(x1) + gml*(H@W2T).
// grid 1024 x 512 thr (8 waves: 2m x 4n). LDS ~72 KB -> 2 blocks/CU.
// ---------------------------------------------------------------------------
__global__ __launch_bounds__(512) void gemm_tail(
    const u16* __restrict__ A, const u16* __restrict__ WoT,
    const u16* __restrict__ W1T, const u16* __restrict__ W2T,
    const float* __restrict__ bo, const float* __restrict__ x,
    const float* __restrict__ gam, const float* __restrict__ lg2,
    const float* __restrict__ lb2, const float* __restrict__ gml,
    float* __restrict__ outx)
{
  __shared__ __align__(16) u16 Blds[256][72];   // weight panel 256n x 64k (+8)
  __shared__ __align__(16) u16 XH[64][256];     // xn, then H (XOR-swizzled)
  __shared__ float LNp[4][64][2];
  __shared__ float LNm[64][2];
  const int m0 = blockIdx.x * 64;
  const int t = threadIdx.x;
  const int wave = t >> 6, lane = t & 63;
  const int wm = (wave & 1) * 32, wn = (wave >> 1) * 64;
  const int lrow = lane & 15, lk = (lane >> 4) * 8;
  const int quad = lane >> 4, col = lane & 15;
  const int brow = t >> 3, bcol = (t & 7) * 8;

  f32x4 acc[2][4];
  #pragma unroll
  for (int i = 0; i < 2; ++i)
    #pragma unroll
    for (int j = 0; j < 4; ++j) acc[i][j] = f32x4{0.f,0.f,0.f,0.f};

  i32x4 rw[4];
#define TL_LOAD(W, p) { \
    _Pragma("unroll") \
    for (int i_ = 0; i_ < 4; ++i_) \
      rw[i_] = *(const i32x4*)((W) + (size_t)(i_*64 + brow) * 256 + (p)*64 + bcol); }
#define TL_STORE() { \
    _Pragma("unroll") \
    for (int i_ = 0; i_ < 4; ++i_) \
      *(i32x4*)(&Blds[i_*64 + brow][bcol]) = rw[i_]; }
#define TL_COMPA(p) { const int k0 = (p)*64; \
    _Pragma("unroll") \
    for (int kk = 0; kk < 64; kk += 32) { \
      s16x8 af[2], bf[4]; \
      _Pragma("unroll") \
      for (int mt = 0; mt < 2; ++mt) \
        af[mt] = *(const s16x8*)(A + (size_t)(m0 + wm + mt*16 + lrow) * 256 + k0 + kk + lk); \
      _Pragma("unroll") \
      for (int nt = 0; nt < 4; ++nt) \
        bf[nt] = *(const s16x8*)(&Blds[wn + nt*16 + lrow][kk + lk]); \
      _Pragma("unroll") \
      for (int mt = 0; mt < 2; ++mt) \
        _Pragma("unroll") \
        for (int nt = 0; nt < 4; ++nt) \
          acc[mt][nt] = __builtin_amdgcn_mfma_f32_16x16x32_bf16(af[mt], bf[nt], acc[mt][nt], 0, 0, 0); } }
#define TL_COMPX(p) { const int k0 = (p)*64; \
    _Pragma("unroll") \
    for (int kk = 0; kk < 64; kk += 32) { \
      s16x8 af[2], bf[4]; \
      _Pragma("unroll") \
      for (int mt = 0; mt < 2; ++mt) { \
        const int row_ = wm + mt*16 + lrow; \
        af[mt] = *(const s16x8*)(&XH[row_][(k0 + kk + lk) ^ ((row_ & 14) << 2)]); } \
      _Pragma("unroll") \
      for (int nt = 0; nt < 4; ++nt) \
        bf[nt] = *(const s16x8*)(&Blds[wn + nt*16 + lrow][kk + lk]); \
      _Pragma("unroll") \
      for (int mt = 0; mt < 2; ++mt) \
        _Pragma("unroll") \
        for (int nt = 0; nt < 4; ++nt) \
          acc[mt][nt] = __builtin_amdgcn_mfma_f32_16x16x32_bf16(af[mt], bf[nt], acc[mt][nt], 0, 0, 0); } }

  // ================= phase A: acc = A @ WoT (pipelined) =================
  TL_LOAD(WoT, 0);
  TL_STORE();
  TL_LOAD(WoT, 1);
  __syncthreads();
  TL_COMPA(0);
  __syncthreads();
  TL_STORE();
  TL_LOAD(WoT, 2);
  __syncthreads();
  TL_COMPA(1);
  __syncthreads();
  TL_STORE();
  TL_LOAD(WoT, 3);
  __syncthreads();
  TL_COMPA(2);
  __syncthreads();
  TL_STORE();
  TL_LOAD(W1T, 0);       // cross-phase prefetch
  __syncthreads();
  TL_COMPA(3);

  // ---- epilogue A: x1 (bf16 in regs) + LN partial sums
  unsigned int x1p[2][4][2];
  float s[2][4], s2[2][4];
  #pragma unroll
  for (int mt = 0; mt < 2; ++mt)
    #pragma unroll
    for (int r = 0; r < 4; ++r) { s[mt][r] = 0.f; s2[mt][r] = 0.f; }

  #pragma unroll
  for (int mt = 0; mt < 2; ++mt) {
    const int mb = m0 + wm + mt*16 + quad*4;
    #pragma unroll
    for (int nt = 0; nt < 4; ++nt) {
      const int n = wn + nt*16 + col;
      const float bon = bo[n], gn = gam[n];
      float v[4];
      #pragma unroll
      for (int r = 0; r < 4; ++r)
        v[r] = x[(size_t)(mb + r) * 256 + n] + gn * (acc[mt][nt][r] + bon);
      const unsigned int p0 = cvt_pk(v[0], v[1]);
      const unsigned int p1 = cvt_pk(v[2], v[3]);
      x1p[mt][nt][0] = p0;
      x1p[mt][nt][1] = p1;
      const float r0 = b2f((u16)(p0 & 0xffffu)), r1 = b2f((u16)(p0 >> 16));
      const float r2 = b2f((u16)(p1 & 0xffffu)), r3 = b2f((u16)(p1 >> 16));
      s[mt][0] += r0; s2[mt][0] += r0 * r0;
      s[mt][1] += r1; s2[mt][1] += r1 * r1;
      s[mt][2] += r2; s2[mt][2] += r2 * r2;
      s[mt][3] += r3; s2[mt][3] += r3 * r3;
    }
  }
  // intra-wave reduce over the 16 col lanes
  #pragma unroll
  for (int off = 1; off <= 8; off <<= 1) {
    #pragma unroll
    for (int mt = 0; mt < 2; ++mt)
      #pragma unroll
      for (int r = 0; r < 4; ++r) {
        s[mt][r]  += __shfl_xor(s[mt][r],  off);
        s2[mt][r] += __shfl_xor(s2[mt][r], off);
      }
  }
  if (col == 0) {
    #pragma unroll
    for (int mt = 0; mt < 2; ++mt)
      #pragma unroll
      for (int r = 0; r < 4; ++r) {
        const int row = wm + mt*16 + quad*4 + r;
        LNp[wave >> 1][row][0] = s[mt][r];
        LNp[wave >> 1][row][1] = s2[mt][r];
      }
  }
  __syncthreads();          // LNp ready; all Blds reads (phase A) done
  TL_STORE();               // W1T panel 0 -> Blds
  TL_LOAD(W1T, 1);
  if (t < 64) {
    const float ss  = LNp[0][t][0] + LNp[1][t][0] + LNp[2][t][0] + LNp[3][t][0];
    const float ss2 = LNp[0][t][1] + LNp[1][t][1] + LNp[2][t][1] + LNp[3][t][1];
    const float mean = ss * 0.00390625f;
    LNm[t][0] = mean;
    LNm[t][1] = rsqrtf(ss2 * 0.00390625f - mean * mean + 1e-5f);
  }
  __syncthreads();          // LNm + Blds(W1 p0) ready
  // xn -> XH (swizzled)
  #pragma unroll
  for (int mt = 0; mt < 2; ++mt) {
    #pragma unroll
    for (int nt = 0; nt < 4; ++nt) {
      const int n = wn + nt*16 + col;
      const float gg = lg2[n], bb_ = lb2[n];
      #pragma unroll
      for (int rr = 0; rr < 2; ++rr) {
        const unsigned int pk = x1p[mt][nt][rr];
        #pragma unroll
        for (int h2 = 0; h2 < 2; ++h2) {
          const int r = rr * 2 + h2;
          const int row = wm + mt*16 + quad*4 + r;
          const float rv = b2f((u16)(h2 ? (pk >> 16) : (pk & 0xffffu)));
          const float xn = (rv - LNm[row][0]) * LNm[row][1] * gg + bb_;
          XH[row][n ^ ((row & 14) << 2)] = f2b(xn);
        }
      }
    }
  }
  #pragma unroll
  for (int i = 0; i < 2; ++i)
    #pragma unroll
    for (int j = 0; j < 4; ++j) acc[i][j] = f32x4{0.f,0.f,0.f,0.f};
  __syncthreads();          // XH ready

  // ================= phase B: acc = XH @ W1T (pipelined) =================
  TL_COMPX(0);
  __syncthreads();
  TL_STORE();               // W1 p1
  TL_LOAD(W1T, 2);
  __syncthreads();
  TL_COMPX(1);
  __syncthreads();
  TL_STORE();               // W1 p2
  TL_LOAD(W1T, 3);
  __syncthreads();
  TL_COMPX(2);
  __syncthreads();
  TL_STORE();               // W1 p3
  TL_LOAD(W2T, 0);          // cross-phase prefetch
  __syncthreads();
  TL_COMPX(3);
  __syncthreads();          // XH reads + Blds reads done
  TL_STORE();               // W2 p0
  TL_LOAD(W2T, 1);
  // silu -> H overwrites XH (swizzled)
  #pragma unroll
  for (int mt = 0; mt < 2; ++mt)
    #pragma unroll
    for (int nt = 0; nt < 4; ++nt)
      #pragma unroll
      for (int r = 0; r < 4; ++r) {
        const float y = acc[mt][nt][r];
        const float hsig = __builtin_amdgcn_rcpf(1.0f + __builtin_amdgcn_exp2f(-1.442695041f * y));
        const int row = wm + mt*16 + quad*4 + r;
        const int n = wn + nt*16 + col;
        XH[row][n ^ ((row & 14) << 2)] = f2b(y * hsig);
        acc[mt][nt][r] = 0.0f;
      }
  __syncthreads();          // H + Blds(W2 p0) ready

  // ================= phase C: acc = H @ W2T (pipelined) =================
  TL_COMPX(0);
  __syncthreads();
  TL_STORE();               // W2 p1
  TL_LOAD(W2T, 2);
  __syncthreads();
  TL_COMPX(1);
  __syncthreads();
  TL_STORE();               // W2 p2
  TL_LOAD(W2T, 3);
  __syncthreads();
  TL_COMPX(2);
  __syncthreads();
  TL_STORE();               // W2 p3
  __syncthreads();
  TL_COMPX(3);

  // ---- epilogue C: out = b2f(x1) + gml[n]*acc
  #pragma unroll
  for (int mt = 0; mt < 2; ++mt) {
    const int mb = m0 + wm + mt*16 + quad*4;
    #pragma unroll
    for (int nt = 0; nt < 4; ++nt) {
      const int n = wn + nt*16 + col;
      const float gn = gml[n];
      #pragma unroll
      for (int rr = 0; rr < 2; ++rr) {
        const unsigned int pk = x1p[mt][nt][rr];
        outx[(size_t)(mb + rr*2    ) * 256 + n] = b2f((u16)(pk & 0xffffu)) + gn * acc[mt][nt][rr*2];
        outx[(size_t)(mb + rr*2 + 1) * 256 + n] = b2f((u16)(pk >> 16))     + gn * acc[mt][nt][rr*2 + 1];
      }
    }
  }
#undef TL_LOAD
#undef TL_STORE
#undef TL_COMPA
#undef TL_COMPX
}

// ---------------------------------------------------------------------------
// Attention v6: flat grid 4096 x 512 thr (8 waves, 16 queries each),
// XCD-aware decode: the 2 blocks sharing a (w,h) K/V slice -> same XCD.
// K+V (32 KB) staged once per block into LDS; swapped-QK register softmax;
// P feeds PV MFMA directly from registers (V key-permuted by gemm_qkv).
// ---------------------------------------------------------------------------
__global__ __launch_bounds__(512) void attn256(
    const u16* __restrict__ q, const u16* __restrict__ k,
    const u16* __restrict__ vt, const float* __restrict__ fbias,
    u16* __restrict__ out)
{
  __shared__ __align__(16) u16 KV[16384];     // K bytes [0,16K) | V bytes [16K,32K)
  __shared__ __align__(16) u16 OB[8][16][40];
  const int bid = blockIdx.x;
  const int xcd = bid & 7, rr = bid >> 3;
  const int q0 = (rr & 1) * 128;
  const int s_ = (rr >> 1) * 8 + xcd;        // 0..2047
  const int h = s_ & 7, w = s_ >> 3;
  const int t = threadIdx.x;
  const int wave = t >> 6, lane = t & 63;
  const int col = lane & 15, quad = lane >> 4;
  const size_t hb = (size_t)w * 65536 + (size_t)h * 8192;
  const int qr0 = q0 + wave * 16;
  const float sc2 = 0.25508586f;  // (1/sqrt(32)) * log2(e)

  // ---- stage K and V (64B per thread each), linear copy
  {
    const char* kg = (const char*)(k + hb);
    const char* vg = (const char*)(vt + hb);
    const i32x4 r0 = *(const i32x4*)(kg + t * 16);
    const i32x4 r1 = *(const i32x4*)(kg + 8192 + t * 16);
    const i32x4 r2 = *(const i32x4*)(vg + t * 16);
    const i32x4 r3 = *(const i32x4*)(vg + 8192 + t * 16);
    char* lb = (char*)KV;
    *(i32x4*)(lb + t * 16)         = r0;
    *(i32x4*)(lb + 8192 + t * 16)  = r1;
    *(i32x4*)(lb + 16384 + t * 16) = r2;
    *(i32x4*)(lb + 24576 + t * 16) = r3;
  }

  // Q fragment + mask bias (global; overlap with stage)
  const s16x8 af = *(const s16x8*)(q + hb + (qr0 + col) * 32 + quad * 8);
  const float* fbb = fbias + w * 256 + quad * 4;
  __syncthreads();

  // ---- QK^T swapped (K from LDS): acc[tl][r] = S[key=tl*16+quad*4+r][q=col]
  f32x4 acc[16];
  #pragma unroll
  for (int tl = 0; tl < 16; ++tl) {
    const s16x8 kf = *(const s16x8*)(KV + (tl * 16 + col) * 32 + quad * 8);
    acc[tl] = __builtin_amdgcn_mfma_f32_16x16x32_bf16(kf, af, f32x4{0.f,0.f,0.f,0.f}, 0, 0, 0);
  }

  // ---- scale + mask bias
  #pragma unroll
  for (int tl = 0; tl < 16; ++tl) {
    const f32x4 fb = *(const f32x4*)(fbb + tl * 16);
    #pragma unroll
    for (int r = 0; r < 4; ++r)
      acc[tl][r] = fmaf(acc[tl][r], sc2, fb[r]);
  }

  // ---- lane-local max over 64 keys, then cross-quad (2 shuffles)
  f32x4 m4 = acc[0];
  #pragma unroll
  for (int tl = 1; tl < 16; ++tl)
    #pragma unroll
    for (int r = 0; r < 4; ++r)
      m4[r] = fmaxf(m4[r], acc[tl][r]);
  float mx = fmaxf(fmaxf(m4[0], m4[1]), fmaxf(m4[2], m4[3]));
  mx = fmaxf(mx, __shfl_xor(mx, 16));
  mx = fmaxf(mx, __shfl_xor(mx, 32));

  // ---- exp2 + lane-local sum, then cross-quad (2 shuffles)
  f32x4 s4 = {0.f, 0.f, 0.f, 0.f};
  #pragma unroll
  for (int tl = 0; tl < 16; ++tl) {
    #pragma unroll
    for (int r = 0; r < 4; ++r) {
      const float e = __builtin_amdgcn_exp2f(acc[tl][r] - mx);
      acc[tl][r] = e;
      s4[r] += e;
    }
  }
  float sum = (s4[0] + s4[1]) + (s4[2] + s4[3]);
  sum += __shfl_xor(sum, 16);
  sum += __shfl_xor(sum, 32);
  const float inv = __builtin_amdgcn_rcpf(sum);

  // ---- PV from registers (V from LDS, pre-permuted)
  f32x4 o0 = {0.f,0.f,0.f,0.f}, o1 = {0.f,0.f,0.f,0.f};
  const u16* vl = KV + 8192;
  #pragma unroll
  for (int s = 0; s < 8; ++s) {
    i32x4 pi;
    pi[0] = (int)cvt_pk(acc[2*s][0],     acc[2*s][1]);
    pi[1] = (int)cvt_pk(acc[2*s][2],     acc[2*s][3]);
    pi[2] = (int)cvt_pk(acc[2*s + 1][0], acc[2*s + 1][1]);
    pi[3] = (int)cvt_pk(acc[2*s + 1][2], acc[2*s + 1][3]);
    const s16x8 pf = *(const s16x8*)&pi;
    const s16x8 vf0 = *(const s16x8*)(vl + s * 1024 + quad * 256 + col * 8);
    const s16x8 vf1 = *(const s16x8*)(vl + s * 1024 + quad * 256 + col * 8 + 128);
    o0 = __builtin_amdgcn_mfma_f32_16x16x32_bf16(pf, vf0, o0, 0, 0, 0);
    o1 = __builtin_amdgcn_mfma_f32_16x16x32_bf16(pf, vf1, o1, 0, 0, 0);
  }

  // ---- 1/sum for output rows q = quad*4+r lives at lane (*, quad*4+r)
  f32x4 invr;
  #pragma unroll
  for (int r = 0; r < 4; ++r) invr[r] = __shfl(inv, quad * 4 + r);

  // ---- bounce O through LDS for 16B/lane stores (wave-private slab)
  #pragma unroll
  for (int r = 0; r < 4; ++r) {
    OB[wave][quad * 4 + r][col]      = f2b(o0[r] * invr[r]);
    OB[wave][quad * 4 + r][col + 16] = f2b(o1[r] * invr[r]);
  }
  const s16x8 ov = *(const s16x8*)(&OB[wave][col][quad * 8]);
  *(s16x8*)(out + (size_t)w * 65536 + (size_t)(qr0 + col) * 256 + h * 32 + quad * 8) = ov;
}

// ---------------------------------------------------------------------------
// mask_update + attention bias precompute. grid 256 x 256.
// ---------------------------------------------------------------------------
__global__ __launch_bounds__(256) void maskup(const int* __restrict__ mask,
                                              float* __restrict__ out,
                                              float* __restrict__ fbias)
{
  __shared__ int wall[4];
  const int w = blockIdx.x, t = threadIdx.x;
  const int v = (mask[w * 256 + t] != 0) ? 1 : 0;
  const int a = __all(v);
  if ((t & 63) == 0) wall[t >> 6] = a;
  __syncthreads();
  const int allw = wall[0] & wall[1] & wall[2] & wall[3];
  out[w * 256 + t] = (v & allw) ? 1.0f : 0.0f;
  fbias[w * 256 + t] = v ? 0.0f : -1.0e9f;
}

// ---------------------------------------------------------------------------
extern "C" void kernel_launch(void* const* d_in, const int* in_sizes, int n_in,
                              void* d_out, int out_size, void* d_ws, size_t ws_size,
                              hipStream_t stream)
{
  (void)in_sizes; (void)n_in; (void)out_size; (void)ws_size;
  const float* x    = (const float*)d_in[0];
  const int*   mask = (const int*)d_in[1];
  const float* pos  = (const float*)d_in[2];
  const float* Wemb = (const float*)d_in[3];
  const float* bemb = (const float*)d_in[4];
  const float* ln1g = (const float*)d_in[5];
  const float* ln1b = (const float*)d_in[6];
  const float* Wq   = (const float*)d_in[7];
  const float* bq   = (const float*)d_in[8];
  const float* Wk   = (const float*)d_in[9];
  const float* bk   = (const float*)d_in[10];
  const float* Wv   = (const float*)d_in[11];
  const float* bv   = (const float*)d_in[12];
  const float* Wo   = (const float*)d_in[13];
  const float* bo   = (const float*)d_in[14];
  const float* ln2g = (const float*)d_in[15];
  const float* ln2b = (const float*)d_in[16];
  const float* W1   = (const float*)d_in[17];
  const float* W2   = (const float*)d_in[18];
  const float* gam  = (const float*)d_in[19];
  const float* gml  = (const float*)d_in[20];

  char* ws = (char*)d_ws;
  float* shift = (float*)ws;                       // 256 KB
  float* scale = (float*)(ws + (256 << 10));       // 256 KB
  u16*   wt    = (u16*)(ws + (512 << 10));         // 768 KB (6 x 256x256)
  float* fbias = (float*)(ws + (1280 << 10));      // 256 KB
  u16*   b0    = (u16*)(ws + ((size_t)2  << 20));  // xm   -> attn_out
  u16*   b1    = (u16*)(ws + ((size_t)34 << 20));  // q^
  u16*   b2    = (u16*)(ws + ((size_t)66 << 20));  // k^
  u16*   b3    = (u16*)(ws + ((size_t)98 << 20));  // V~
  float* outx  = (float*)d_out;
  float* outm  = outx + 16777216;

  const u16* WoT = wt + 3 * 65536;
  const u16* W1T = wt + 4 * 65536;
  const u16* W2T = wt + 5 * 65536;

  transpose6<<<dim3(6, 16), 256, 0, stream>>>(Wq, Wk, Wv, Wo, W1, W2, wt);
  film_kernel<<<dim3(256, 8), 256, 0, stream>>>(pos, Wemb, bemb, shift, scale);
  maskup<<<256, 256, 0, stream>>>(mask, outm, fbias);
  ln_kernel<<<4096, 256, 0, stream>>>(x, shift, scale, ln1g, ln1b, b0);
  gemm_qkv<<<3072, 256, 0, stream>>>(b0, wt, bq, bk, bv, b1, b2, b3);
  attn256<<<4096, 512, 0, stream>>>(b1, b2, b3, fbias, b0);
  // fused tail: Wo-residual + LN2 + MLP, single pass over the activations
  gemm_tail<<<1024, 512, 0, stream>>>(b0, WoT, W1T, W2T, bo, x, gam,
                                      ln2g, ln2b, gml, outx);
}